// Round 1
// baseline (1084.525 us; speedup 1.0000x reference)
//
#include <hip/hip_runtime.h>

#define NN 50000
#define EE 1600000
#define HD 256
#define LN_EPS 1e-5f
#define NSCAN 98   // ceil(50000/512)

// ---------------- degree histogram ----------------
__global__ void deg_kernel(const int* __restrict__ src, const int* __restrict__ dst,
                           int* __restrict__ deg_out, int* __restrict__ deg_in) {
    int e = blockIdx.x * 256 + threadIdx.x;
    if (e < EE) {
        atomicAdd(&deg_out[src[e]], 1);
        atomicAdd(&deg_in[dst[e]], 1);
    }
}

// ---------------- 3-stage exclusive scan of deg_in -> rowptr ----------------
__global__ void scan_part(const int* __restrict__ deg_in, int* __restrict__ parts) {
    int t = threadIdx.x;
    int i0 = blockIdx.x * 512 + t * 2;
    int v0 = (i0     < NN) ? deg_in[i0]     : 0;
    int v1 = (i0 + 1 < NN) ? deg_in[i0 + 1] : 0;
    int s = v0 + v1;
    #pragma unroll
    for (int off = 32; off > 0; off >>= 1) s += __shfl_xor(s, off);
    __shared__ int wsum[4];
    int lane = t & 63, wv = t >> 6;
    if (lane == 0) wsum[wv] = s;
    __syncthreads();
    if (t == 0) parts[blockIdx.x] = wsum[0] + wsum[1] + wsum[2] + wsum[3];
}

__global__ void scan_mid(const int* __restrict__ parts, int* __restrict__ partoff) {
    int run = 0;
    for (int i = 0; i < NSCAN; i++) { partoff[i] = run; run += parts[i]; }
}

__global__ void scan_final(const int* __restrict__ deg_in, const int* __restrict__ partoff,
                           int* __restrict__ rowptr) {
    int t = threadIdx.x;
    int lane = t & 63, wv = t >> 6;
    int i0 = blockIdx.x * 512 + t * 2;
    int v0 = (i0     < NN) ? deg_in[i0]     : 0;
    int v1 = (i0 + 1 < NN) ? deg_in[i0 + 1] : 0;
    int s = v0 + v1;
    // inclusive scan within wave
    int sc = s;
    #pragma unroll
    for (int off = 1; off < 64; off <<= 1) {
        int nv = __shfl_up(sc, off);
        if (lane >= off) sc += nv;
    }
    __shared__ int wS[4];
    if (lane == 63) wS[wv] = sc;
    __syncthreads();
    if (t == 0) {
        int run = 0;
        #pragma unroll
        for (int w = 0; w < 4; w++) { int tmp = wS[w]; wS[w] = run; run += tmp; }
    }
    __syncthreads();
    int excl = sc - s + wS[wv] + partoff[blockIdx.x];
    if (i0     < NN) rowptr[i0]     = excl;
    if (i0 + 1 < NN) rowptr[i0 + 1] = excl + v0;
}

__global__ void fill_csr(const int* __restrict__ src, const int* __restrict__ dst,
                         const int* __restrict__ rowptr, int* __restrict__ cursor,
                         int* __restrict__ csr_src) {
    int e = blockIdx.x * 256 + threadIdx.x;
    if (e < EE) {
        int d = dst[e];
        int pos = rowptr[d] + atomicAdd(&cursor[d], 1);
        csr_src[pos] = src[e];
    }
}

// ---------------- fp32 GEMM: Y = (X * rsqrt(max(deg,1))) @ W ----------------
// BM=64 rows, BN=128 cols, BK=32; 256 threads; per-thread 4x8 register tile.
__global__ __launch_bounds__(256) void gemm_scaled(
    const float* __restrict__ X, const float* __restrict__ W,
    const int* __restrict__ deg, float* __restrict__ Y)
{
    __shared__ float Xs[64][33];
    __shared__ float Ws[32][128];
    __shared__ float sS[64];
    int t = threadIdx.x;
    int row0 = blockIdx.x * 64;
    int j0 = blockIdx.y * 128;
    if (t < 64) {
        int row = row0 + t;
        int dg = (row < NN) ? deg[row] : 1;
        sS[t] = rsqrtf((float)(dg > 1 ? dg : 1));
    }
    int tc = t & 15, tr = t >> 4;
    float acc[4][8];
    #pragma unroll
    for (int i = 0; i < 4; i++)
        #pragma unroll
        for (int j = 0; j < 8; j++) acc[i][j] = 0.f;
    __syncthreads();
    for (int k0 = 0; k0 < HD; k0 += 32) {
        #pragma unroll
        for (int i = 0; i < 8; i++) {
            int flat = i * 256 + t;
            int r = flat >> 5, kk = flat & 31;
            int row = row0 + r;
            float v = (row < NN) ? X[row * HD + k0 + kk] : 0.f;
            Xs[r][kk] = v * sS[r];
        }
        #pragma unroll
        for (int i = 0; i < 16; i++) {
            int flat = i * 256 + t;
            int kk = flat >> 7, j = flat & 127;
            Ws[kk][j] = W[(k0 + kk) * HD + j0 + j];
        }
        __syncthreads();
        #pragma unroll
        for (int kk = 0; kk < 32; kk++) {
            float a0 = Xs[tr * 4 + 0][kk];
            float a1 = Xs[tr * 4 + 1][kk];
            float a2 = Xs[tr * 4 + 2][kk];
            float a3 = Xs[tr * 4 + 3][kk];
            float4 bb0 = *(const float4*)&Ws[kk][tc * 8];
            float4 bb1 = *(const float4*)&Ws[kk][tc * 8 + 4];
            float b[8] = {bb0.x, bb0.y, bb0.z, bb0.w, bb1.x, bb1.y, bb1.z, bb1.w};
            #pragma unroll
            for (int j = 0; j < 8; j++) {
                acc[0][j] += a0 * b[j];
                acc[1][j] += a1 * b[j];
                acc[2][j] += a2 * b[j];
                acc[3][j] += a3 * b[j];
            }
        }
        __syncthreads();
    }
    #pragma unroll
    for (int i = 0; i < 4; i++) {
        int row = row0 + tr * 4 + i;
        if (row < NN) {
            float4 u0 = {acc[i][0], acc[i][1], acc[i][2], acc[i][3]};
            float4 u1 = {acc[i][4], acc[i][5], acc[i][6], acc[i][7]};
            *(float4*)&Y[row * HD + j0 + tc * 8]     = u0;
            *(float4*)&Y[row * HD + j0 + tc * 8 + 4] = u1;
        }
    }
}

// ---------------- CSR gather aggregation, fused epilogues ----------------
// MODE 0: out = relu(sum * rsqrt(deg_in) + bias)
// MODE 1: out = LayerNorm(sum * rsqrt(deg_in) + bias) * gamma + beta
template <int MODE>
__global__ __launch_bounds__(256) void aggregate_kernel(
    const float* __restrict__ Yin, const int* __restrict__ rowptr,
    const int* __restrict__ deg_in, const int* __restrict__ csr_src,
    const float* __restrict__ bias, const float* __restrict__ gamma,
    const float* __restrict__ beta, float* __restrict__ out)
{
    int wv = threadIdx.x >> 6, lane = threadIdx.x & 63;
    int n = blockIdx.x * 4 + wv;
    if (n >= NN) return;
    int start = rowptr[n];
    int cnt = deg_in[n];
    float4 acc = make_float4(0.f, 0.f, 0.f, 0.f);
    const float4* base = (const float4*)Yin;
    for (int i = 0; i < cnt; i++) {
        int s = csr_src[start + i];
        float4 v = base[s * 64 + lane];
        acc.x += v.x; acc.y += v.y; acc.z += v.z; acc.w += v.w;
    }
    float scl = rsqrtf((float)(cnt > 1 ? cnt : 1));
    float4 b = ((const float4*)bias)[lane];
    float4 r;
    r.x = acc.x * scl + b.x;
    r.y = acc.y * scl + b.y;
    r.z = acc.z * scl + b.z;
    r.w = acc.w * scl + b.w;
    if (MODE == 0) {
        r.x = fmaxf(r.x, 0.f); r.y = fmaxf(r.y, 0.f);
        r.z = fmaxf(r.z, 0.f); r.w = fmaxf(r.w, 0.f);
        ((float4*)out)[n * 64 + lane] = r;
    } else {
        float s1 = r.x + r.y + r.z + r.w;
        #pragma unroll
        for (int off = 1; off < 64; off <<= 1) s1 += __shfl_xor(s1, off);
        float mu = s1 * (1.f / 256.f);
        float d0 = r.x - mu, d1 = r.y - mu, d2 = r.z - mu, d3 = r.w - mu;
        float s2 = d0 * d0 + d1 * d1 + d2 * d2 + d3 * d3;
        #pragma unroll
        for (int off = 1; off < 64; off <<= 1) s2 += __shfl_xor(s2, off);
        float rs = rsqrtf(s2 * (1.f / 256.f) + LN_EPS);
        float4 g  = ((const float4*)gamma)[lane];
        float4 be = ((const float4*)beta)[lane];
        float4 o;
        o.x = d0 * rs * g.x + be.x;
        o.y = d1 * rs * g.y + be.y;
        o.z = d2 * rs * g.z + be.z;
        o.w = d3 * rs * g.w + be.w;
        ((float4*)out)[n * 64 + lane] = o;
    }
}

extern "C" void kernel_launch(void* const* d_in, const int* in_sizes, int n_in,
                              void* d_out, int out_size, void* d_ws, size_t ws_size,
                              hipStream_t stream)
{
    const float* x     = (const float*)d_in[0];
    const float* W1    = (const float*)d_in[1];
    const float* b1    = (const float*)d_in[2];
    const float* W2    = (const float*)d_in[3];
    const float* b2    = (const float*)d_in[4];
    const float* gamma = (const float*)d_in[5];
    const float* beta  = (const float*)d_in[6];
    const int*   src   = (const int*)d_in[7];
    const int*   dst   = (const int*)d_in[8];
    float* out = (float*)d_out;

    // workspace layout (ints then one big float buffer); total ~58.4 MB
    int* deg_out = (int*)d_ws;          // N
    int* deg_in  = deg_out + NN;        // N
    int* cursor  = deg_in + NN;         // N   (zeroed)
    int* rowptr  = cursor + NN;         // N
    int* parts   = rowptr + NN;         // 128
    int* partoff = parts + 128;         // 128
    int* csr_src = partoff + 128;       // E
    float* bufA  = (float*)(csr_src + EE);  // N*256 f32

    // zero deg_out, deg_in, cursor (they are the first 3*N ints)
    hipMemsetAsync(d_ws, 0, (size_t)3 * NN * sizeof(int), stream);

    deg_kernel<<<(EE + 255) / 256, 256, 0, stream>>>(src, dst, deg_out, deg_in);
    scan_part <<<NSCAN, 256, 0, stream>>>(deg_in, parts);
    scan_mid  <<<1, 1, 0, stream>>>(parts, partoff);
    scan_final<<<NSCAN, 256, 0, stream>>>(deg_in, partoff, rowptr);
    fill_csr  <<<(EE + 255) / 256, 256, 0, stream>>>(src, dst, rowptr, cursor, csr_src);

    dim3 gg((NN + 63) / 64, 2);
    // layer 1: bufA = (x * deg_out^-1/2) @ W1 ; out(hact) = relu(aggr(bufA)*deg_in^-1/2 + b1)
    gemm_scaled<<<gg, 256, 0, stream>>>(x, W1, deg_out, bufA);
    aggregate_kernel<0><<<(NN + 3) / 4, 256, 0, stream>>>(bufA, rowptr, deg_in, csr_src,
                                                          b1, nullptr, nullptr, out);
    // layer 2: bufA = (hact * deg_out^-1/2) @ W2 ; out = LN(aggr(bufA)*deg_in^-1/2 + b2)
    gemm_scaled<<<gg, 256, 0, stream>>>(out, W2, deg_out, bufA);
    aggregate_kernel<1><<<(NN + 3) / 4, 256, 0, stream>>>(bufA, rowptr, deg_in, csr_src,
                                                          b2, gamma, beta, out);
}

// Round 2
// 675.955 us; speedup vs baseline: 1.6044x; 1.6044x over previous
//
#include <hip/hip_runtime.h>

#define NN 50000
#define EE 1600000
#define HD 256
#define MPAD 50048      // 391 * 128
#define LN_EPS 1e-5f
#define NSCAN 98        // ceil(50000/512)

typedef unsigned short ushort_t;
typedef unsigned int uint_t;

using frag_ab = __attribute__((ext_vector_type(8))) short;   // 8 bf16
using frag_cd = __attribute__((ext_vector_type(4))) float;   // 4 f32
using f32x4   = __attribute__((ext_vector_type(4))) float;

__device__ __forceinline__ ushort_t f2bf(float f) {
    uint_t u = __float_as_uint(f);
    uint_t r = (u + 0x7FFFu + ((u >> 16) & 1u)) >> 16;
    return (ushort_t)r;
}
__device__ __forceinline__ float blo(uint_t u) { return __uint_as_float(u << 16); }
__device__ __forceinline__ float bhi(uint_t u) { return __uint_as_float(u & 0xFFFF0000u); }

// ---------------- degree histogram ----------------
__global__ void deg_kernel(const int* __restrict__ src, const int* __restrict__ dst,
                           int* __restrict__ deg_out, int* __restrict__ deg_in) {
    int e = blockIdx.x * 256 + threadIdx.x;
    if (e < EE) {
        atomicAdd(&deg_out[src[e]], 1);
        atomicAdd(&deg_in[dst[e]], 1);
    }
}

// ---------------- 3-stage exclusive scan of deg_in -> rowptr ----------------
__global__ void scan_part(const int* __restrict__ deg_in, int* __restrict__ parts) {
    int t = threadIdx.x;
    int i0 = blockIdx.x * 512 + t * 2;
    int v0 = (i0     < NN) ? deg_in[i0]     : 0;
    int v1 = (i0 + 1 < NN) ? deg_in[i0 + 1] : 0;
    int s = v0 + v1;
    #pragma unroll
    for (int off = 32; off > 0; off >>= 1) s += __shfl_xor(s, off);
    __shared__ int wsum[4];
    int lane = t & 63, wv = t >> 6;
    if (lane == 0) wsum[wv] = s;
    __syncthreads();
    if (t == 0) parts[blockIdx.x] = wsum[0] + wsum[1] + wsum[2] + wsum[3];
}

__global__ void scan_mid(const int* __restrict__ parts, int* __restrict__ partoff) {
    int run = 0;
    for (int i = 0; i < NSCAN; i++) { partoff[i] = run; run += parts[i]; }
}

__global__ void scan_final(const int* __restrict__ deg_in, const int* __restrict__ partoff,
                           int* __restrict__ rowptr) {
    int t = threadIdx.x;
    int lane = t & 63, wv = t >> 6;
    int i0 = blockIdx.x * 512 + t * 2;
    int v0 = (i0     < NN) ? deg_in[i0]     : 0;
    int v1 = (i0 + 1 < NN) ? deg_in[i0 + 1] : 0;
    int s = v0 + v1;
    int sc = s;
    #pragma unroll
    for (int off = 1; off < 64; off <<= 1) {
        int nv = __shfl_up(sc, off);
        if (lane >= off) sc += nv;
    }
    __shared__ int wS[4];
    if (lane == 63) wS[wv] = sc;
    __syncthreads();
    if (t == 0) {
        int run = 0;
        #pragma unroll
        for (int w = 0; w < 4; w++) { int tmp = wS[w]; wS[w] = run; run += tmp; }
    }
    __syncthreads();
    int excl = sc - s + wS[wv] + partoff[blockIdx.x];
    if (i0     < NN) rowptr[i0]     = excl;
    if (i0 + 1 < NN) rowptr[i0 + 1] = excl + v0;
}

// fill CSR; uses rowptr itself as the cursor -> afterwards rowptr[n] = row END
__global__ void fill_csr(const int* __restrict__ src, const int* __restrict__ dst,
                         int* __restrict__ rowptr, int* __restrict__ csr_src) {
    int e = blockIdx.x * 256 + threadIdx.x;
    if (e < EE) {
        int d = dst[e];
        int pos = atomicAdd(&rowptr[d], 1);
        csr_src[pos] = src[e];
    }
}

// ---------------- W convert + transpose: Wt[n][k] = bf16(W[k][n]) ----------------
__global__ void wconv(const float* __restrict__ W, ushort_t* __restrict__ Wt) {
    int g = blockIdx.x * 256 + threadIdx.x;   // 65536 threads
    int k = g >> 8, n = g & 255;
    Wt[n * 256 + k] = f2bf(W[g]);
}

// ---------------- bf16 MFMA GEMM: Y[bf16] = (A @ Wt^T) * rsqrt(max(deg,1)) per row
// A: fp32 [NN][256] (A_BF16=0) or bf16 [MPAD][256] (A_BF16=1); Wt: bf16 [256 n][256 k]
// 128x128 tile, 4 waves (2x2), each wave 64x64 (4x4 frags of 16x16), BK=64.
__device__ __forceinline__ int swz(int r, int kElem) {
    return ((r * 64 + kElem) * 2) ^ ((r & 7) << 4);
}

template <int A_BF16>
__global__ __launch_bounds__(256) void gemm_mfma(
    const void* __restrict__ Aptr, const ushort_t* __restrict__ Wt,
    const int* __restrict__ deg, ushort_t* __restrict__ Y)
{
    __shared__ __align__(16) ushort_t As[8192];   // 128 rows x 64 k (swizzled)
    __shared__ __align__(16) ushort_t Bs[8192];   // 128 cols x 64 k (swizzled)
    __shared__ float sS[128];

    int t = threadIdx.x;
    int lane = t & 63, wid = t >> 6;
    int wm = wid >> 1, wn = wid & 1;
    int row0 = blockIdx.x * 128;
    int col0 = blockIdx.y * 128;

    if (t < 128) {
        int row = row0 + t;
        int dg = (row < NN) ? deg[row] : 1;
        sS[t] = rsqrtf((float)(dg > 1 ? dg : 1));
    }

    frag_cd acc[4][4];
    #pragma unroll
    for (int m = 0; m < 4; m++)
        #pragma unroll
        for (int n = 0; n < 4; n++) acc[m][n] = (frag_cd)(0.f);

    const float*    Af = (const float*)Aptr;
    const ushort_t* Ab = (const ushort_t*)Aptr;

    for (int k0 = 0; k0 < HD; k0 += 64) {
        __syncthreads();
        // stage A (convert fp32->bf16 if needed)
        #pragma unroll
        for (int i = 0; i < 8; i++) {
            int flat = i * 256 + t;
            int r = flat >> 4;
            int k4 = (flat & 15) * 4;
            int row = row0 + r;
            ushort4 u;
            if constexpr (!A_BF16) {
                float4 v = make_float4(0.f, 0.f, 0.f, 0.f);
                if (row < NN) v = *(const float4*)&Af[(size_t)row * 256 + k0 + k4];
                u.x = f2bf(v.x); u.y = f2bf(v.y); u.z = f2bf(v.z); u.w = f2bf(v.w);
            } else {
                if (row < NN) u = *(const ushort4*)&Ab[(size_t)row * 256 + k0 + k4];
                else u = make_ushort4(0, 0, 0, 0);
            }
            *(ushort4*)((char*)As + swz(r, k4)) = u;
        }
        // stage B from Wt (already bf16, [n][k])
        #pragma unroll
        for (int i = 0; i < 8; i++) {
            int flat = i * 256 + t;
            int nn = flat >> 4;
            int k4 = (flat & 15) * 4;
            ushort4 u = *(const ushort4*)&Wt[(size_t)(col0 + nn) * 256 + k0 + k4];
            *(ushort4*)((char*)Bs + swz(nn, k4)) = u;
        }
        __syncthreads();
        #pragma unroll
        for (int s = 0; s < 2; s++) {
            int kb = s * 32 + ((lane >> 4) * 8);
            frag_ab af[4], bfr[4];
            #pragma unroll
            for (int m = 0; m < 4; m++) {
                int r = wm * 64 + m * 16 + (lane & 15);
                af[m] = *(const frag_ab*)((const char*)As + swz(r, kb));
            }
            #pragma unroll
            for (int n = 0; n < 4; n++) {
                int c = wn * 64 + n * 16 + (lane & 15);
                bfr[n] = *(const frag_ab*)((const char*)Bs + swz(c, kb));
            }
            #pragma unroll
            for (int m = 0; m < 4; m++)
                #pragma unroll
                for (int n = 0; n < 4; n++)
                    acc[m][n] = __builtin_amdgcn_mfma_f32_16x16x32_bf16(
                        af[m], bfr[n], acc[m][n], 0, 0, 0);
        }
    }

    // epilogue: row-scale by deg_out^-1/2, cast bf16, store
    #pragma unroll
    for (int m = 0; m < 4; m++) {
        int rl = wm * 64 + m * 16 + ((lane >> 4) * 4);
        #pragma unroll
        for (int j = 0; j < 4; j++) {
            float sc = sS[rl + j];
            size_t grow = (size_t)(row0 + rl + j);
            #pragma unroll
            for (int n = 0; n < 4; n++) {
                int gcol = col0 + wn * 64 + n * 16 + (lane & 15);
                Y[grow * 256 + gcol] = f2bf(acc[m][n][j] * sc);
            }
        }
    }
}

// ---------------- CSR gather aggregation (bf16 messages), fused epilogues --------
// MODE 0: h[bf16] = relu(sum * rsqrt(deg_in) + bias)
// MODE 1: out[f32] = LayerNorm(sum * rsqrt(deg_in) + bias) * gamma + beta
template <int MODE>
__global__ __launch_bounds__(256) void aggregate_kernel(
    const ushort_t* __restrict__ msg, const int* __restrict__ rowend,
    const int* __restrict__ deg_in, const int* __restrict__ csr_src,
    const float* __restrict__ bias, const float* __restrict__ gamma,
    const float* __restrict__ beta, void* __restrict__ outp)
{
    int wv = threadIdx.x >> 6, lane = threadIdx.x & 63;
    int n = blockIdx.x * 4 + wv;
    if (n >= NN) return;
    int end = rowend[n];
    int cnt = deg_in[n];
    int i = end - cnt;
    float a0 = 0.f, a1 = 0.f, a2 = 0.f, a3 = 0.f;
    const uint2* base = (const uint2*)msg;   // 8B (4 bf16) per lane

    for (; i + 8 <= end; i += 8) {
        int ss[8];
        #pragma unroll
        for (int u = 0; u < 8; u++) ss[u] = csr_src[i + u];
        uint2 vv[8];
        #pragma unroll
        for (int u = 0; u < 8; u++) vv[u] = base[(size_t)ss[u] * 64 + lane];
        #pragma unroll
        for (int u = 0; u < 8; u++) {
            a0 += blo(vv[u].x); a1 += bhi(vv[u].x);
            a2 += blo(vv[u].y); a3 += bhi(vv[u].y);
        }
    }
    for (; i < end; i++) {
        int s = csr_src[i];
        uint2 v = base[(size_t)s * 64 + lane];
        a0 += blo(v.x); a1 += bhi(v.x); a2 += blo(v.y); a3 += bhi(v.y);
    }

    float scl = rsqrtf((float)(cnt > 1 ? cnt : 1));
    float4 b = ((const float4*)bias)[lane];
    float r0 = a0 * scl + b.x;
    float r1 = a1 * scl + b.y;
    float r2 = a2 * scl + b.z;
    float r3 = a3 * scl + b.w;

    if (MODE == 0) {
        r0 = fmaxf(r0, 0.f); r1 = fmaxf(r1, 0.f);
        r2 = fmaxf(r2, 0.f); r3 = fmaxf(r3, 0.f);
        uint2 o;
        o.x = (uint_t)f2bf(r0) | ((uint_t)f2bf(r1) << 16);
        o.y = (uint_t)f2bf(r2) | ((uint_t)f2bf(r3) << 16);
        ((uint2*)outp)[(size_t)n * 64 + lane] = o;
    } else {
        float s1 = r0 + r1 + r2 + r3;
        #pragma unroll
        for (int off = 1; off < 64; off <<= 1) s1 += __shfl_xor(s1, off);
        float mu = s1 * (1.f / 256.f);
        float d0 = r0 - mu, d1 = r1 - mu, d2 = r2 - mu, d3 = r3 - mu;
        float s2 = d0 * d0 + d1 * d1 + d2 * d2 + d3 * d3;
        #pragma unroll
        for (int off = 1; off < 64; off <<= 1) s2 += __shfl_xor(s2, off);
        float rs = rsqrtf(s2 * (1.f / 256.f) + LN_EPS);
        float4 g  = ((const float4*)gamma)[lane];
        float4 be = ((const float4*)beta)[lane];
        float4 o;
        o.x = d0 * rs * g.x + be.x;
        o.y = d1 * rs * g.y + be.y;
        o.z = d2 * rs * g.z + be.z;
        o.w = d3 * rs * g.w + be.w;
        ((float4*)outp)[(size_t)n * 64 + lane] = o;
    }
}

extern "C" void kernel_launch(void* const* d_in, const int* in_sizes, int n_in,
                              void* d_out, int out_size, void* d_ws, size_t ws_size,
                              hipStream_t stream)
{
    const float* x     = (const float*)d_in[0];
    const float* W1    = (const float*)d_in[1];
    const float* b1    = (const float*)d_in[2];
    const float* W2    = (const float*)d_in[3];
    const float* b2    = (const float*)d_in[4];
    const float* gamma = (const float*)d_in[5];
    const float* beta  = (const float*)d_in[6];
    const int*   src   = (const int*)d_in[7];
    const int*   dst   = (const int*)d_in[8];
    float* out = (float*)d_out;

    // ws layout (~33 MB)
    int* deg_out = (int*)d_ws;               // N
    int* deg_in  = deg_out + NN;             // N
    int* rowptr  = deg_in + NN;              // N  (becomes row END after fill_csr)
    int* parts   = rowptr + NN;              // 128
    int* partoff = parts + 128;              // 128
    int* csr_src = partoff + 128;            // E
    ushort_t* Wt1 = (ushort_t*)(csr_src + EE);   // 65536 bf16
    ushort_t* Wt2 = Wt1 + 65536;                 // 65536 bf16
    ushort_t* msg = Wt2 + 65536;                 // MPAD*256 bf16  (25.6 MB)

    // layer-1 activation h (bf16) lives in the first half of d_out; it is fully
    // consumed by gemm2 before the final LN write overwrites it.
    ushort_t* h = (ushort_t*)d_out;

    hipMemsetAsync(d_ws, 0, (size_t)2 * NN * sizeof(int), stream);   // deg_out, deg_in

    deg_kernel<<<(EE + 255) / 256, 256, 0, stream>>>(src, dst, deg_out, deg_in);
    scan_part <<<NSCAN, 256, 0, stream>>>(deg_in, parts);
    scan_mid  <<<1, 1, 0, stream>>>(parts, partoff);
    scan_final<<<NSCAN, 256, 0, stream>>>(deg_in, partoff, rowptr);
    fill_csr  <<<(EE + 255) / 256, 256, 0, stream>>>(src, dst, rowptr, csr_src);

    wconv<<<256, 256, 0, stream>>>(W1, Wt1);
    wconv<<<256, 256, 0, stream>>>(W2, Wt2);

    dim3 gg(MPAD / 128, 2);
    gemm_mfma<0><<<gg, 256, 0, stream>>>(x, Wt1, deg_out, msg);
    aggregate_kernel<0><<<(NN + 3) / 4, 256, 0, stream>>>(msg, rowptr, deg_in, csr_src,
                                                          b1, nullptr, nullptr, h);
    gemm_mfma<1><<<gg, 256, 0, stream>>>(h, Wt2, deg_out, msg);
    aggregate_kernel<1><<<(NN + 3) / 4, 256, 0, stream>>>(msg, rowptr, deg_in, csr_src,
                                                          b2, gamma, beta, out);
}

// Round 4
// 487.898 us; speedup vs baseline: 2.2229x; 1.3854x over previous
//
#include <hip/hip_runtime.h>

#define NN 50000
#define EE 1600000
#define HD 256
#define MPAD 50048      // 391 * 128
#define LN_EPS 1e-5f

#define NB 256          // coarse buckets
#define BR 196          // node range per bucket (256*196 = 50176 >= 50048)
#define NBLK 128        // radix count/scatter blocks
#define CH 12500        // edges per block (128*12500 = 1.6M)
#define SL 16           // src slices
#define SSH 12          // src >> 12  (4096 nodes/slice = 2MB bf16 msg slice)
#define FB 3136         // fine bins = BR*SL
#define FBP 3328        // padded to 256*13
#define CF 13           // fine scan chunk per thread

typedef unsigned short ushort_t;
typedef unsigned int uint_t;

using frag_ab = __attribute__((ext_vector_type(8))) short;   // 8 bf16
using frag_cd = __attribute__((ext_vector_type(4))) float;   // 4 f32

__device__ __forceinline__ ushort_t f2bf(float f) {
    uint_t u = __float_as_uint(f);
    uint_t r = (u + 0x7FFFu + ((u >> 16) & 1u)) >> 16;
    return (ushort_t)r;
}
__device__ __forceinline__ float blo(uint_t u) { return __uint_as_float(u << 16); }
__device__ __forceinline__ float bhi(uint_t u) { return __uint_as_float(u & 0xFFFF0000u); }

// ============ radix pass 1: coarse counts (src & dst), no global atomics ======
__global__ __launch_bounds__(256) void radix_count(
    const int* __restrict__ src, const int* __restrict__ dst,
    int* __restrict__ cntD, int* __restrict__ cntS)
{
    __shared__ int hD[NB], hS[NB];
    int t = threadIdx.x, blk = blockIdx.x;
    hD[t] = 0; hS[t] = 0;
    __syncthreads();
    for (int i = t; i < CH; i += 256) {
        int e = blk * CH + i;
        atomicAdd(&hD[dst[e] / BR], 1);
        atomicAdd(&hS[src[e] / BR], 1);
    }
    __syncthreads();
    cntD[t * NBLK + blk] = hD[t];   // bucket-major layout
    cntS[t * NBLK + blk] = hS[t];
}

// ============ radix scan: exclusive scan of 32768 (bucket-major) ==============
__global__ __launch_bounds__(256) void radix_scan(
    const int* __restrict__ cntD, int* __restrict__ scanD, int* __restrict__ bbD,
    const int* __restrict__ cntS, int* __restrict__ scanS, int* __restrict__ bbS)
{
    const int* cnt = (blockIdx.x == 0) ? cntD : cntS;
    int* scn       = (blockIdx.x == 0) ? scanD : scanS;
    int* bb        = (blockIdx.x == 0) ? bbD : bbS;
    int t = threadIdx.x, lane = t & 63, wv = t >> 6;
    int base = t * NBLK;
    int s = 0;
    for (int j = 0; j < NBLK; j++) s += cnt[base + j];
    int sc = s;
    #pragma unroll
    for (int off = 1; off < 64; off <<= 1) {
        int nv = __shfl_up(sc, off);
        if (lane >= off) sc += nv;
    }
    __shared__ int wp[4];
    if (lane == 63) wp[wv] = sc;
    __syncthreads();
    int wb = 0;
    for (int w = 0; w < wv; w++) wb += wp[w];
    int run = wb + sc - s;          // exclusive base for this thread's chunk
    bb[t] = run;                    // chunk start == bucket t start
    for (int j = 0; j < NBLK; j++) { scn[base + j] = run; run += cnt[base + j]; }
    if (t == 255) bb[256] = run;    // total = EE
}

// ============ radix scatter: partition edges by dst (pairs) and src (keys) ====
__global__ __launch_bounds__(256) void radix_scatter(
    const int* __restrict__ src, const int* __restrict__ dst,
    const int* __restrict__ scanD, const int* __restrict__ scanS,
    uint2* __restrict__ dpart, int* __restrict__ spart)
{
    __shared__ int curD[NB], curS[NB];
    int t = threadIdx.x, blk = blockIdx.x;
    curD[t] = scanD[t * NBLK + blk];
    curS[t] = scanS[t * NBLK + blk];
    __syncthreads();
    for (int i = t; i < CH; i += 256) {
        int e = blk * CH + i;
        int sv = src[e], dv = dst[e];
        int pd = atomicAdd(&curD[dv / BR], 1);
        dpart[pd] = make_uint2((uint_t)sv, (uint_t)dv);
        int ps = atomicAdd(&curS[sv / BR], 1);
        spart[ps] = sv;
    }
}

// ============ fine stage (dst): per-bucket CSR sorted by (dst, src-slice) =====
// writes rp16[node*16 + slice] global sub-row starts and csr_src placement
__global__ __launch_bounds__(256) void fine_dst(
    const uint2* __restrict__ dpart, const int* __restrict__ bbD,
    int* __restrict__ rp16, int* __restrict__ csr_src)
{
    __shared__ int hist[FBP];
    __shared__ int cur[FBP];
    __shared__ int wp[4];
    int t = threadIdx.x, lane = t & 63, wv = t >> 6;
    int b = blockIdx.x;
    int bb = bbD[b];
    int cnt = bbD[b + 1] - bb;
    int node0 = b * BR;
    #pragma unroll
    for (int j = 0; j < CF; j++) hist[t * CF + j] = 0;
    __syncthreads();
    for (int i = t; i < cnt; i += 256) {
        uint2 p = dpart[bb + i];
        int bin = ((int)p.y - node0) * SL + ((int)p.x >> SSH);
        atomicAdd(&hist[bin], 1);
    }
    __syncthreads();
    // block exclusive scan over FBP bins (chunk CF per thread)
    int vals[CF];
    int s = 0;
    #pragma unroll
    for (int j = 0; j < CF; j++) { vals[j] = hist[t * CF + j]; s += vals[j]; }
    int sc = s;
    #pragma unroll
    for (int off = 1; off < 64; off <<= 1) {
        int nv = __shfl_up(sc, off);
        if (lane >= off) sc += nv;
    }
    if (lane == 63) wp[wv] = sc;
    __syncthreads();
    int wb = 0;
    for (int w = 0; w < wv; w++) wb += wp[w];
    int run = wb + sc - s;
    #pragma unroll
    for (int j = 0; j < CF; j++) {
        int bin = t * CF + j;
        cur[bin] = run;
        if (bin < FB) rp16[b * FB + bin] = bb + run;
        run += vals[j];
    }
    __syncthreads();
    for (int i = t; i < cnt; i += 256) {
        uint2 p = dpart[bb + i];
        int bin = ((int)p.y - node0) * SL + ((int)p.x >> SSH);
        int pos = bb + atomicAdd(&cur[bin], 1);
        csr_src[pos] = (int)p.x;
    }
}

// ============ fine stage (src): per-bucket histogram -> deg_out ===============
__global__ __launch_bounds__(256) void fine_src(
    const int* __restrict__ spart, const int* __restrict__ bbS,
    int* __restrict__ deg_out)
{
    __shared__ int hist[NB];
    int t = threadIdx.x, b = blockIdx.x;
    hist[t] = 0;
    __syncthreads();
    int bb = bbS[b];
    int cnt = bbS[b + 1] - bb;
    int node0 = b * BR;
    for (int i = t; i < cnt; i += 256) atomicAdd(&hist[spart[bb + i] - node0], 1);
    __syncthreads();
    if (t < BR) deg_out[node0 + t] = hist[t];
}

// ---------------- W convert + transpose: Wt[n][k] = bf16(W[k][n]) ----------------
__global__ void wconv(const float* __restrict__ W, ushort_t* __restrict__ Wt) {
    int g = blockIdx.x * 256 + threadIdx.x;
    int k = g >> 8, n = g & 255;
    Wt[n * 256 + k] = f2bf(W[g]);
}

// ---------------- bf16 MFMA GEMM ----------------
__device__ __forceinline__ int swz(int r, int kElem) {
    return ((r * 64 + kElem) * 2) ^ ((r & 7) << 4);
}

template <int A_BF16>
__global__ __launch_bounds__(256) void gemm_mfma(
    const void* __restrict__ Aptr, const ushort_t* __restrict__ Wt,
    const int* __restrict__ deg, ushort_t* __restrict__ Y)
{
    __shared__ __align__(16) ushort_t As[8192];
    __shared__ __align__(16) ushort_t Bs[8192];
    __shared__ float sS[128];

    int t = threadIdx.x;
    int lane = t & 63, wid = t >> 6;
    int wm = wid >> 1, wn = wid & 1;
    int row0 = blockIdx.x * 128;
    int col0 = blockIdx.y * 128;

    if (t < 128) {
        int row = row0 + t;
        int dg = (row < NN) ? deg[row] : 1;
        sS[t] = rsqrtf((float)(dg > 1 ? dg : 1));
    }

    frag_cd acc[4][4];
    #pragma unroll
    for (int m = 0; m < 4; m++)
        #pragma unroll
        for (int n = 0; n < 4; n++) acc[m][n] = (frag_cd)(0.f);

    const float*    Af = (const float*)Aptr;
    const ushort_t* Ab = (const ushort_t*)Aptr;

    for (int k0 = 0; k0 < HD; k0 += 64) {
        __syncthreads();
        #pragma unroll
        for (int i = 0; i < 8; i++) {
            int flat = i * 256 + t;
            int r = flat >> 4;
            int k4 = (flat & 15) * 4;
            int row = row0 + r;
            ushort4 u;
            if constexpr (!A_BF16) {
                float4 v = make_float4(0.f, 0.f, 0.f, 0.f);
                if (row < NN) v = *(const float4*)&Af[(size_t)row * 256 + k0 + k4];
                u.x = f2bf(v.x); u.y = f2bf(v.y); u.z = f2bf(v.z); u.w = f2bf(v.w);
            } else {
                if (row < NN) u = *(const ushort4*)&Ab[(size_t)row * 256 + k0 + k4];
                else u = make_ushort4(0, 0, 0, 0);
            }
            *(ushort4*)((char*)As + swz(r, k4)) = u;
        }
        #pragma unroll
        for (int i = 0; i < 8; i++) {
            int flat = i * 256 + t;
            int nn = flat >> 4;
            int k4 = (flat & 15) * 4;
            ushort4 u = *(const ushort4*)&Wt[(size_t)(col0 + nn) * 256 + k0 + k4];
            *(ushort4*)((char*)Bs + swz(nn, k4)) = u;
        }
        __syncthreads();
        #pragma unroll
        for (int s = 0; s < 2; s++) {
            int kb = s * 32 + ((lane >> 4) * 8);
            frag_ab af[4], bfr[4];
            #pragma unroll
            for (int m = 0; m < 4; m++) {
                int r = wm * 64 + m * 16 + (lane & 15);
                af[m] = *(const frag_ab*)((const char*)As + swz(r, kb));
            }
            #pragma unroll
            for (int n = 0; n < 4; n++) {
                int c = wn * 64 + n * 16 + (lane & 15);
                bfr[n] = *(const frag_ab*)((const char*)Bs + swz(c, kb));
            }
            #pragma unroll
            for (int m = 0; m < 4; m++)
                #pragma unroll
                for (int n = 0; n < 4; n++)
                    acc[m][n] = __builtin_amdgcn_mfma_f32_16x16x32_bf16(
                        af[m], bfr[n], acc[m][n], 0, 0, 0);
        }
    }

    #pragma unroll
    for (int m = 0; m < 4; m++) {
        int rl = wm * 64 + m * 16 + ((lane >> 4) * 4);
        #pragma unroll
        for (int j = 0; j < 4; j++) {
            float sc = sS[rl + j];
            size_t grow = (size_t)(row0 + rl + j);
            #pragma unroll
            for (int n = 0; n < 4; n++) {
                int gcol = col0 + wn * 64 + n * 16 + (lane & 15);
                Y[grow * 256 + gcol] = f2bf(acc[m][n][j] * sc);
            }
        }
    }
}

// ---------------- CSR gather aggregation (bf16 messages, slice-sorted CSR) ----
template <int MODE>
__global__ __launch_bounds__(256) void aggregate_kernel(
    const ushort_t* __restrict__ msg, const int* __restrict__ rp16,
    const int* __restrict__ csr_src,
    const float* __restrict__ bias, const float* __restrict__ gamma,
    const float* __restrict__ beta, void* __restrict__ outp)
{
    int wv = threadIdx.x >> 6, lane = threadIdx.x & 63;
    int n = blockIdx.x * 4 + wv;
    if (n >= NN) return;
    int start = rp16[n * SL];
    int end   = rp16[n * SL + SL];
    int cnt = end - start;
    int i = start;
    float a0 = 0.f, a1 = 0.f, a2 = 0.f, a3 = 0.f;
    const uint2* base = (const uint2*)msg;

    for (; i + 8 <= end; i += 8) {
        int ss[8];
        #pragma unroll
        for (int u = 0; u < 8; u++) ss[u] = csr_src[i + u];
        uint2 vv[8];
        #pragma unroll
        for (int u = 0; u < 8; u++) vv[u] = base[(size_t)ss[u] * 64 + lane];
        #pragma unroll
        for (int u = 0; u < 8; u++) {
            a0 += blo(vv[u].x); a1 += bhi(vv[u].x);
            a2 += blo(vv[u].y); a3 += bhi(vv[u].y);
        }
    }
    for (; i < end; i++) {
        int s = csr_src[i];
        uint2 v = base[(size_t)s * 64 + lane];
        a0 += blo(v.x); a1 += bhi(v.x); a2 += blo(v.y); a3 += bhi(v.y);
    }

    float scl = rsqrtf((float)(cnt > 1 ? cnt : 1));
    float4 b = ((const float4*)bias)[lane];
    float r0 = a0 * scl + b.x;
    float r1 = a1 * scl + b.y;
    float r2 = a2 * scl + b.z;
    float r3 = a3 * scl + b.w;

    if (MODE == 0) {
        r0 = fmaxf(r0, 0.f); r1 = fmaxf(r1, 0.f);
        r2 = fmaxf(r2, 0.f); r3 = fmaxf(r3, 0.f);
        uint2 o;
        o.x = (uint_t)f2bf(r0) | ((uint_t)f2bf(r1) << 16);
        o.y = (uint_t)f2bf(r2) | ((uint_t)f2bf(r3) << 16);
        ((uint2*)outp)[(size_t)n * 64 + lane] = o;
    } else {
        float s1 = r0 + r1 + r2 + r3;
        #pragma unroll
        for (int off = 1; off < 64; off <<= 1) s1 += __shfl_xor(s1, off);
        float mu = s1 * (1.f / 256.f);
        float d0 = r0 - mu, d1 = r1 - mu, d2 = r2 - mu, d3 = r3 - mu;
        float s2 = d0 * d0 + d1 * d1 + d2 * d2 + d3 * d3;
        #pragma unroll
        for (int off = 1; off < 64; off <<= 1) s2 += __shfl_xor(s2, off);
        float rs = rsqrtf(s2 * (1.f / 256.f) + LN_EPS);
        float4 g  = ((const float4*)gamma)[lane];
        float4 be = ((const float4*)beta)[lane];
        float4 o;
        o.x = d0 * rs * g.x + be.x;
        o.y = d1 * rs * g.y + be.y;
        o.z = d2 * rs * g.z + be.z;
        o.w = d3 * rs * g.w + be.w;
        ((float4*)outp)[(size_t)n * 64 + lane] = o;
    }
}

extern "C" void kernel_launch(void* const* d_in, const int* in_sizes, int n_in,
                              void* d_out, int out_size, void* d_ws, size_t ws_size,
                              hipStream_t stream)
{
    const float* x     = (const float*)d_in[0];
    const float* W1    = (const float*)d_in[1];
    const float* b1    = (const float*)d_in[2];
    const float* W2    = (const float*)d_in[3];
    const float* b2    = (const float*)d_in[4];
    const float* gamma = (const float*)d_in[5];
    const float* beta  = (const float*)d_in[6];
    const int*   src   = (const int*)d_in[7];
    const int*   dst   = (const int*)d_in[8];
    float* out = (float*)d_out;

    // ws layout (~55 MB)
    uint2*    dpart  = (uint2*)d_ws;                         // EE uint2   12.8MB
    ushort_t* msg    = (ushort_t*)(dpart + EE);              // MPAD*256   25.6MB
    int*      csr    = (int*)(msg + (size_t)MPAD * 256);     // EE          6.4MB
    int*      spart  = csr + EE;                             // EE          6.4MB
    int*      rp16   = spart + EE;                           // 256*FB      3.2MB
    int*      cntD   = rp16 + NB * FB + 16;
    int*      cntS   = cntD + NB * NBLK;
    int*      scanD  = cntS + NB * NBLK;
    int*      scanS  = scanD + NB * NBLK;
    int*      bbD    = scanS + NB * NBLK;                    // 320 (257 used)
    int*      bbS    = bbD + 320;                            // 320
    int*      degout = bbS + 320;                            // 50176
    ushort_t* Wt1    = (ushort_t*)(degout + NB * BR);        // 65536 bf16
    ushort_t* Wt2    = Wt1 + 65536;                          // 65536 bf16

    ushort_t* h = (ushort_t*)d_out;   // layer-1 activation (bf16) in d_out

    radix_count  <<<NBLK, 256, 0, stream>>>(src, dst, cntD, cntS);
    radix_scan   <<<2, 256, 0, stream>>>(cntD, scanD, bbD, cntS, scanS, bbS);
    radix_scatter<<<NBLK, 256, 0, stream>>>(src, dst, scanD, scanS, dpart, spart);
    fine_dst     <<<NB, 256, 0, stream>>>(dpart, bbD, rp16, csr);
    fine_src     <<<NB, 256, 0, stream>>>(spart, bbS, degout);

    wconv<<<256, 256, 0, stream>>>(W1, Wt1);
    wconv<<<256, 256, 0, stream>>>(W2, Wt2);

    dim3 gg(MPAD / 128, 2);
    gemm_mfma<0><<<gg, 256, 0, stream>>>(x, Wt1, degout, msg);
    aggregate_kernel<0><<<(NN + 3) / 4, 256, 0, stream>>>(msg, rp16, csr,
                                                          b1, nullptr, nullptr, h);
    gemm_mfma<1><<<gg, 256, 0, stream>>>(h, Wt2, degout, msg);
    aggregate_kernel<1><<<(NN + 3) / 4, 256, 0, stream>>>(msg, rp16, csr,
                                                          b2, gamma, beta, out);
}